// Round 5
// baseline (93.325 us; speedup 1.0000x reference)
//
#include <hip/hip_runtime.h>
#include <math.h>

#define BLK 256
#define SBLK 64               /* setup block size: more blocks -> more CUs on f64 latency */
#define G 32
#define NMODES 6400
#define STRIPE (NMODES / G)   /* 200 */
#define MDIM 80
#define TILE 2048             /* samples per block (x) */
#define SPT 8                 /* samples per thread = TILE/BLK */

// Persistent device-global mode tables (rewritten every call).
// Records are stored PERMUTED: slot gy*STRIPE + j holds raw mode gy + G*j,
// so modal block gy reads a contiguous, coalesced 200x16B run.
__device__ float4   g_rec1[NMODES];   // {w_rev_hi, w_rev_lo, z=-sig*K*log2e, A}
__device__ float4   g_rec2[NMODES];   // {cos(256*w), sin(256*w), 2^(256*z), 0}
__device__ unsigned g_maxbits;
__device__ unsigned g_done;

// Raw gfx950 transcendentals. v_sin/v_cos input is REVOLUTIONS (sin(x*2pi)),
// pre-reduced with v_fract. v_exp_f32: D = 2^S0.
__device__ __forceinline__ float v_fract(float x){ float r; asm("v_fract_f32 %0, %1" : "=v"(r) : "v"(x)); return r; }
__device__ __forceinline__ float v_sin_rev(float x){ float r; asm("v_sin_f32 %0, %1" : "=v"(r) : "v"(x)); return r; }
__device__ __forceinline__ float v_cos_rev(float x){ float r; asm("v_cos_f32 %0, %1" : "=v"(r) : "v"(x)); return r; }
__device__ __forceinline__ float v_exp2(float x){ float r; asm("v_exp_f32 %0, %1" : "=v"(r) : "v"(x)); return r; }

__device__ __forceinline__ double softplus_d(double x) {
    return (x > 30.0) ? x : log1p(exp(x));
}

// Dispatch 1: derive all 6400 mode records once (f64), reset sync slots.
__global__ __launch_bounds__(SBLK) void setup_kernel(
    const float* __restrict__ mu_raw_p, const float* __restrict__ Dmu_raw_p,
    const float* __restrict__ T0mu_raw_p, const float* __restrict__ Ly_raw_p,
    const float* __restrict__ xo_raw_p, const float* __restrict__ yo_raw_p)
{
    const int gid = blockIdx.x * SBLK + threadIdx.x;
    if (gid == 0) { g_maxbits = 0u; g_done = 0u; }
    if (gid >= NMODES) return;

    const double PI_D     = 3.14159265358979323846;
    const double TWO_PI_D = 6.28318530717958647693;
    const double INV2PI_D = 0.15915494309189533577;
    const double LOG2E_D  = 1.44269504088896340736;
    const double LX = 0.5;
    const double Kd = 1.0 / 44100.0;
    const double MAX_OM = 10000.0 * TWO_PI_D;
    const double MIN_OM = 20.0 * TWO_PI_D;

    // float32-rounded constants, exactly as the reference bakes them
    const double OM2   = TWO_PI_D * 500.0;
    const double DOMSQ = OM2 * OM2;
    const float ALPHA_F = (float)(3.0 * log(10.0) / DOMSQ * (OM2 * OM2 / 6.0));
    const float BETA_F  = (float)(3.0 * log(10.0) / DOMSQ * (1.0 / 1.0 - 1.0 / 6.0));

    const double mu   = softplus_d((double)mu_raw_p[0])  + 1e-4;
    const double Dmu  = softplus_d((double)Dmu_raw_p[0]) + 1e-4;
    const double T0mu = softplus_d((double)T0mu_raw_p[0]) + 1e-4;
    const double Ly   = 1.1 + (4.0 - 1.1) * ((tanh((double)Ly_raw_p[0]) + 1.0) * 0.5);
    const double xo   = 0.49 * LX + (1.0 - 0.49) * LX * ((tanh((double)xo_raw_p[0]) + 1.0) * 0.5);
    const double yo   = 0.51 * Ly + (1.0 - 0.51) * Ly * ((tanh((double)yo_raw_p[0]) + 1.0) * 0.5);
    const double xi = 0.1 * LX;
    const double yi = 0.1 * Ly;
    const double ms = 0.25 * mu * LX * Ly;

    const double mm = (double)(gid / MDIM + 1);   // M_VEC
    const double nn = (double)(gid % MDIM + 1);   // N_VEC
    const double a1 = mm * PI_D / LX;
    const double a2 = nn * PI_D / Ly;
    const double g1 = a1 * a1 + a2 * a2;
    double osq = T0mu * g1 + Dmu * g1 * g1;
    if (osq < 0.0) osq = 0.0;
    const double omega = sqrt(osq);

    float4 r1 = make_float4(0.0f, 0.0f, 0.0f, 0.0f);
    float4 r2 = make_float4(1.0f, 0.0f, 1.0f, 0.0f);
    if (omega >= MIN_OM && omega <= MAX_OM) {
        const double w     = omega * Kd;
        const double sig   = (double)ALPHA_F + (double)BETA_F * (omega * omega);
        const double in_w  = cos(xi * a1) * cos(yi * a2);
        const double out_w = cos(xo * a1) * cos(yo * a2);
        const double denom = sin(w) + 1e-8;
        // term_n = A * exp(-sig*K*n) * sin(n*w)
        const double A = out_w * in_w * (Kd * Kd) / ms / denom;
        const double wrev = w * INV2PI_D;
        const float hi = (float)wrev;
        const float lo = (float)(wrev - (double)hi);
        const double z = -sig * Kd * LOG2E_D;            // log2 decay per sample
        const double dph = 256.0 * w;                    // 256-sample step (radians)
        r1 = make_float4(hi, lo, (float)z, (float)A);
        r2 = make_float4((float)cos(dph), (float)sin(dph),
                         (float)exp2(256.0 * z), 0.0f);
    }
    // permuted store: raw mode gid = gy + G*j  ->  slot gy*STRIPE + j
    const int slot = (gid % G) * STRIPE + (gid / G);
    g_rec1[slot] = r1;
    g_rec2[slot] = r2;
}

// Dispatch 2: grid (ceil(N/2048), G). Block (bx,gy) computes samples
// [bx*2048, bx*2048+2048) over mode stripe gy; thread t covers samples
// t+256k (k=0..7) via sin/cos rotation + exp recurrence. Private partial
// row per gy in d_ws — no atomics.
__global__ __launch_bounds__(BLK) void modal_main_kernel(
    float* __restrict__ partial, int pstride)
{
    __shared__ float4 md1[STRIPE];
    __shared__ float4 md2[STRIPE];
    __shared__ int cnt;
    if (threadIdx.x == 0) cnt = 0;
    __syncthreads();

    const int n0  = blockIdx.x * TILE;
    const int gy  = blockIdx.y;
    const float n0f = (float)n0;
    const int lane = threadIdx.x & 63;

    {   // STRIPE (200) <= BLK: single compaction pass, wave-aggregated,
        // coalesced reads from the permuted record table.
        const int j = threadIdx.x;
        bool alive = false;
        float4 o1, o2;
        if (j < STRIPE) {
            const float4 rec = g_rec1[gy * STRIPE + j];
            if (rec.w != 0.0f) {
                const float amp0 = rec.w * v_exp2(rec.z * n0f);  // decay to tile base
                if (fabsf(amp0) >= 1e-20f) {
                    const double wrev = (double)rec.x + (double)rec.y;
                    const double p0   = (double)n0 * wrev;
                    const float base  = (float)(p0 - rint(p0));  // phase base (revs)
                    o1 = make_float4(base, rec.x, rec.z, amp0);
                    o2 = g_rec2[gy * STRIPE + j];
                    alive = true;
                }
            }
        }
        const unsigned long long mask = __ballot(alive);
        const int nw = __popcll(mask);
        int base_slot = 0;
        if (lane == 0 && nw) base_slot = atomicAdd(&cnt, nw);
        base_slot = __shfl(base_slot, 0, 64);
        if (alive) {
            const int s = base_slot + __popcll(mask & ((1ull << lane) - 1ull));
            md1[s] = o1;
            md2[s] = o2;
        }
    }
    __syncthreads();

    const int count = cnt;
    const float tf = (float)threadIdx.x;
    float acc[SPT];
    #pragma unroll
    for (int k = 0; k < SPT; ++k) acc[k] = 0.0f;

    for (int j = 0; j < count; ++j) {
        const float4 v1 = md1[j];                // broadcast LDS reads
        const float4 v2 = md2[j];
        const float rev = v_fract(fmaf(tf, v1.y, v1.x));
        float s = v_sin_rev(rev);
        float c = v_cos_rev(rev);
        float amp = v1.w * v_exp2(v1.z * tf);
        const float cD = v2.x, sD = v2.y, eD = v2.z;
        acc[0] = fmaf(amp, s, acc[0]);
        #pragma unroll
        for (int k = 1; k < SPT; ++k) {          // rotate +256 samples, decay
            const float sn = fmaf(s, cD,  c * sD);
            const float cn = fmaf(c, cD, -s * sD);
            s = sn; c = cn;
            amp *= eD;
            acc[k] = fmaf(amp, s, acc[k]);
        }
    }
    // Unconditional coalesced stores into this block's private slice of row gy
    // (pstride is a multiple of TILE; rows fully rewritten every call, so the
    // 0xAA ws poison is never read).
    float* row = partial + (size_t)gy * pstride + n0 + threadIdx.x;
    #pragma unroll
    for (int k = 0; k < SPT; ++k) row[k * 256] = acc[k];
}

// Dispatch 3 (fused): out[n] = sum_g partial[g][n]; grid-wide max via
// atomicMax + done-counter spin (all blocks co-resident: 44 blocks << 256
// CUs); then scale in-registers and store out ONCE.
__global__ __launch_bounds__(BLK) void combine_scale_kernel(
    const float* __restrict__ partial, int pstride,
    float* __restrict__ out, int N, unsigned nblocks)
{
    const int nvec = N >> 2;
    const int i = blockIdx.x * BLK + threadIdx.x;
    float4 s = make_float4(0.0f, 0.0f, 0.0f, 0.0f);
    float m = 0.0f;
    const bool has = (i < nvec);
    if (has) {
        const float4* p4 = (const float4*)partial;
        const int vstride = pstride >> 2;
        #pragma unroll
        for (int g = 0; g < G; ++g) {
            const float4 v = p4[(size_t)g * vstride + i];
            s.x += v.x; s.y += v.y; s.z += v.z; s.w += v.w;
        }
        m = fmaxf(fmaxf(fabsf(s.x), fabsf(s.y)), fmaxf(fabsf(s.z), fabsf(s.w)));
    }
    float tail = 0.0f;
    const bool has_tail = (blockIdx.x == 0 && threadIdx.x < (N & 3));
    if (has_tail) {
        const int n = (nvec << 2) + threadIdx.x;
        for (int g = 0; g < G; ++g) tail += partial[(size_t)g * pstride + n];
        m = fmaxf(m, fabsf(tail));
    }
    // block-level max
    #pragma unroll
    for (int o = 32; o > 0; o >>= 1) m = fmaxf(m, __shfl_down(m, o));
    __shared__ float sm[4];
    __shared__ float s_inv;
    const int w = threadIdx.x >> 6, l = threadIdx.x & 63;
    if (l == 0) sm[w] = m;
    __syncthreads();
    if (threadIdx.x == 0) {
        const float bm = fmaxf(fmaxf(sm[0], sm[1]), fmaxf(sm[2], sm[3]));
        atomicMax(&g_maxbits, __float_as_uint(bm));   // device-scope
        __threadfence();                              // release
        atomicAdd(&g_done, 1u);
        while (atomicAdd(&g_done, 0u) < nblocks) {}   // spin on coherent RMW
        __threadfence();                              // acquire
        const float peak = __uint_as_float(atomicMax(&g_maxbits, 0u));
        s_inv = 1.0f / (peak + 1e-8f);
    }
    __syncthreads();
    const float inv = s_inv;
    if (has) {
        s.x *= inv; s.y *= inv; s.z *= inv; s.w *= inv;
        ((float4*)out)[i] = s;
    }
    if (has_tail) out[(nvec << 2) + threadIdx.x] = tail * inv;
}

extern "C" void kernel_launch(void* const* d_in, const int* in_sizes, int n_in,
                              void* d_out, int out_size, void* d_ws, size_t ws_size,
                              hipStream_t stream) {
    const float* mu_raw   = (const float*)d_in[0];
    const float* Dmu_raw  = (const float*)d_in[1];
    const float* T0mu_raw = (const float*)d_in[2];
    const float* Ly_raw   = (const float*)d_in[3];
    const float* xo_raw   = (const float*)d_in[4];
    const float* yo_raw   = (const float*)d_in[5];
    float* out = (float*)d_out;
    float* partial = (float*)d_ws;       // G rows x pstride floats (~5.8 MB)
    const int N = out_size;

    const int ntiles  = (N + TILE - 1) / TILE;
    const int pstride = ntiles * TILE;
    const int nb_setup = (NMODES + SBLK - 1) / SBLK;   // 100 blocks -> 100 CUs
    int nbv = ((N >> 2) + BLK - 1) / BLK;
    if (nbv < 1) nbv = 1;

    setup_kernel<<<nb_setup, SBLK, 0, stream>>>(mu_raw, Dmu_raw, T0mu_raw,
                                                Ly_raw, xo_raw, yo_raw);
    modal_main_kernel<<<dim3(ntiles, G), BLK, 0, stream>>>(partial, pstride);
    combine_scale_kernel<<<nbv, BLK, 0, stream>>>(partial, pstride, out, N,
                                                  (unsigned)nbv);
}